// Round 29
// baseline (59.908 us; speedup 1.0000x reference)
//
#include <hip/hip_runtime.h>
#include <hip/hip_bf16.h>
#include <stdint.h>
#include <stddef.h>

#define BATCH 4
#define SEQ   2048
#define DM    512
#define NST   64
#define LN_EPS 1e-5f
#define NCH   32
#define KDIM  192

typedef __attribute__((ext_vector_type(8))) short short8;
typedef __attribute__((ext_vector_type(4))) float f32x4;

__device__ __forceinline__ ushort f2bf(float f) {
    __hip_bfloat16 h = __float2bfloat16(f);
    return *(ushort*)&h;
}
__device__ __forceinline__ float bf2f(ushort u) {
    __hip_bfloat16 h = *(__hip_bfloat16*)&u;
    return __bfloat162float(h);
}

// ---------------- k_prep: x-transpose + W-convert ----------------
__global__ __launch_bounds__(256) void k_prep(
    const float* __restrict__ x, const float* __restrict__ W,
    __hip_bfloat16* __restrict__ xT, __hip_bfloat16* __restrict__ Wbf)
{
    __shared__ float smem[64][33];
    const int tid = threadIdx.x;
    const int bid = blockIdx.x;

    if (bid < 2048) {
        const int dt = bid & 15, lt = (bid >> 4) & 31, b = bid >> 9;
        const int l0 = lt * 64, d0 = dt * 32;
        const int dd = tid & 31, lr = tid >> 5;
        #pragma unroll
        for (int it = 0; it < 8; ++it) {
            int ll = it * 8 + lr;
            smem[ll][dd] = x[((size_t)b * SEQ + l0 + ll) * DM + d0 + dd];
        }
        __syncthreads();
        const int dw = tid >> 3, lg = (tid & 7) * 8;
        ushort pk[8];
        #pragma unroll
        for (int i = 0; i < 8; ++i) pk[i] = f2bf(smem[lg + i][dw]);
        *(short8*)&xT[((size_t)(d0 + dw) * BATCH + b) * SEQ + l0 + lg] = *(short8*)pk;
    } else {
        int i = (bid - 2048) * 256 + tid;
        if (i < DM * DM) Wbf[i] = __float2bfloat16(W[i]);
    }
}

// ---------------- k_ssm v3: 512 threads, in-block G/M build + 3 MFMA phases (round-26 proven) ----------------
__global__ __launch_bounds__(512) void k_ssm(
    const float* __restrict__ logA, const float* __restrict__ Aim,
    const float* __restrict__ Bp, const float* __restrict__ Cp,
    const __hip_bfloat16* __restrict__ xT, const float* __restrict__ Dp,
    __hip_bfloat16* __restrict__ yT)
{
    __shared__ short Zs[128 * 24 * 8];             // 48K: x chunks 0-7, carry chunks 8-23
    __shared__ __align__(16) char Rgn[128 * 129 * 4];   // 64.5K union: Gs / Us / Ms
    __shared__ float Klds[64];
    __shared__ float2 e64s[64];
    short* Gs = (short*)Rgn;
    float (*Us)[129] = (float(*)[129])Rgn;
    short* Ms = (short*)Rgn;

    const int tid = threadIdx.x;
    const int d = blockIdx.x;
    const int w = tid >> 6, lane = tid & 63;
    const int q = lane >> 4, n = lane & 15;

    // ---- issue Zs x-part loads early (land during G build) ----
    short8 xr[2];
    #pragma unroll
    for (int it = 0; it < 2; ++it) {
        int id = it * 512 + tid;
        int col = id >> 3, ck = id & 7;
        int bb = col >> 5, ch = col & 31;
        xr[it] = *(const short8*)&xT[((size_t)d * BATCH + bb) * SEQ + ch * 64 + ck * 8];
    }

    // ---- build G rows (2s,2s+1) chunk w, K partials, carry entries; wave j covers t in [8j,8j+8) ----
    uint mca[8];
    {
        const int s = lane;
        const int i = d * NST + s;
        float aa  = expf(logA[i]);
        float wim = Aim[i];
        float mag = expf(-aa);
        float er = mag * cosf(wim), ei = mag * sinf(wim);
        float Br = Bp[2*i], Bi = Bp[2*i+1];
        float Cr = Cp[2*i], Ci = Cp[2*i+1];
        float CBr = Cr*Br + Ci*Bi;
        float CBi = Cr*Bi - Ci*Br;

        float e2r = er*er - ei*ei,   e2i = 2.f*er*ei;
        float e4r = e2r*e2r - e2i*e2i, e4i = 2.f*e2r*e2i;
        float e8r = e4r*e4r - e4i*e4i, e8i = 2.f*e4r*e4i;       // eA^8
        float ar, ai;
        if (w == 0)      { ar = 1.f;  ai = 0.f; }
        else if (w == 1) { ar = e8r;  ai = e8i; }
        else {
            float e16r = e8r*e8r - e8i*e8i, e16i = 2.f*e8r*e8i;
            if (w == 2)      { ar = e16r; ai = e16i; }
            else if (w == 3) { ar = e16r*e8r - e16i*e8i;  ai = e16r*e8i + e16i*e8r; }
            else {
                float e32r = e16r*e16r - e16i*e16i, e32i = 2.f*e16r*e16i;
                if (w == 4)      { ar = e32r; ai = e32i; }
                else if (w == 5) { ar = e32r*e8r - e32i*e8i;   ai = e32r*e8i + e32i*e8r; }
                else if (w == 6) { ar = e32r*e16r - e32i*e16i; ai = e32r*e16i + e32i*e16r; }
                else {
                    float e48r = e32r*e16r - e32i*e16i, e48i = e32r*e16i + e32i*e16r;
                    ar = e48r*e8r - e48i*e8i;  ai = e48r*e8i + e48i*e8r;   // eA^56
                }
            }
        }
        float prr = CBr*ar - CBi*ai;
        float pii = CBr*ai + CBi*ar;

        float kb[8];
        ushort gR[8], gI[8];
        #pragma unroll
        for (int tt = 0; tt < 8; ++tt) {
            kb[tt] = prr;
            gR[tt] = f2bf(prr);
            gI[tt] = f2bf(pii);
            float npr = er*prr - ei*pii, npi = er*pii + ei*prr;  prr = npr; pii = npi;
            float nar = er*ar - ei*ai,   nai = er*ai + ei*ar;    ar = nar; ai = nai;
            mca[tt] = (uint)f2bf(ar) | ((uint)f2bf(-ai) << 16);
        }
        if (w == 7) e64s[s] = make_float2(ar, ai);

        short8 v;
        int row = 2 * s;
        #pragma unroll
        for (int e = 0; e < 8; ++e) v[e] = (short)gR[e];
        { int cs = w ^ (row & 7); *(short8*)&Gs[(row * 8 + cs) * 8] = v; }
        row = 2 * s + 1;
        #pragma unroll
        for (int e = 0; e < 8; ++e) v[e] = (short)gI[e];
        { int cs = w ^ (row & 7); *(short8*)&Gs[(row * 8 + cs) * 8] = v; }

        #pragma unroll
        for (int tt = 0; tt < 8; ++tt) {
            float v2 = kb[tt];
            #pragma unroll
            for (int mask = 1; mask < 64; mask <<= 1) v2 += __shfl_xor(v2, mask);
            if (lane == 0) Klds[8 * w + tt] = v2;
        }
    }

    // ---- write Zs x-part from prefetched regs ----
    #pragma unroll
    for (int it = 0; it < 2; ++it) {
        int id = it * 512 + tid;
        int col = id >> 3, ck = id & 7;
        int cs = ck ^ (col & 7);
        *(short8*)&Zs[(col * 24 + cs) * 8] = xr[it];
    }
    __syncthreads();

    // ---- phase 1: U = G * X (wave w owns rows 16w..16w+15) ----
    f32x4 acc1[8];
    {
        #pragma unroll
        for (int nf = 0; nf < 8; ++nf)
            #pragma unroll
            for (int k = 0; k < 4; ++k) acc1[nf][k] = 0.f;

        const int arow = w * 16 + n;
        #pragma unroll
        for (int kt = 0; kt < 2; ++kt) {
            int c = kt * 4 + q;
            int csa = c ^ (arow & 7);
            short8 af = *(const short8*)&Gs[(arow * 8 + csa) * 8];
            #pragma unroll
            for (int nf = 0; nf < 8; ++nf) {
                int col = nf * 16 + n;
                int csb = c ^ (col & 7);
                short8 bf = *(const short8*)&Zs[(col * 24 + csb) * 8];
                acc1[nf] = __builtin_amdgcn_mfma_f32_16x16x32_bf16(af, bf, acc1[nf], 0, 0, 0);
            }
        }
    }
    __syncthreads();

    {
        const int r0w = w * 16 + q * 4;
        #pragma unroll
        for (int nf = 0; nf < 8; ++nf) {
            int col = nf * 16 + n;
            #pragma unroll
            for (int r = 0; r < 4; ++r) Us[r0w + r][col] = acc1[nf][r];
        }
    }
    __syncthreads();

    // ---- phase 2: carry combine (tid<256) ----
    if (tid < 256) {
        const int bb = tid >> 6, s = tid & 63;
        const int st = s >> 2, so = (s & 3) * 2;
        float2 a64 = e64s[s];
        const float er = a64.x, ei = a64.y;
        {
            int col = bb * 32 + 31;
            int c = 8 + st, cs = (c & ~7) | ((c & 7) ^ (col & 7));
            *(uint*)&Zs[(col * 24 + cs) * 8 + so] = 0u;
        }
        float gr = Us[2 * s][bb * 32 + 31], gi = Us[2 * s + 1][bb * 32 + 31];
        {
            int col = bb * 32 + 30;
            int c = 8 + st, cs = (c & ~7) | ((c & 7) ^ (col & 7));
            *(uint*)&Zs[(col * 24 + cs) * 8 + so] = (uint)f2bf(gr) | ((uint)f2bf(gi) << 16);
        }
        #pragma unroll 6
        for (int ch = 30; ch >= 1; --ch) {
            float ur = Us[2 * s][bb * 32 + ch], ui = Us[2 * s + 1][bb * 32 + ch];
            float nr = ur + er * gr - ei * gi;
            float ni = ui + er * gi + ei * gr;
            gr = nr; gi = ni;
            int col = bb * 32 + ch - 1;
            int c = 8 + st, cs = (c & ~7) | ((c & 7) ^ (col & 7));
            *(uint*)&Zs[(col * 24 + cs) * 8 + so] = (uint)f2bf(gr) | ((uint)f2bf(gi) << 16);
        }
    }
    __syncthreads();

    // ---- build Ms ----
    {
        {
            int id = tid;
            int row = id >> 3, c = id & 7;
            short8 v;
            #pragma unroll
            for (int e = 0; e < 8; ++e) {
                int col = c * 8 + e;
                float kv = (col >= row) ? Klds[col - row] : 0.f;
                v[e] = (short)f2bf(kv);
            }
            int cs = c ^ (row & 7);
            *(short8*)&Ms[(row * 24 + cs) * 8] = v;
        }
        const int s = lane;
        const int cc = 8 + (s >> 2);
        const int soff = 2 * (s & 3);
        #pragma unroll
        for (int tt = 0; tt < 8; ++tt) {
            int row = 63 - (8 * w + tt);
            int cs = (cc & ~7) | ((cc & 7) ^ (row & 7));
            *(uint*)&Ms[(row * 24 + cs) * 8 + soff] = mca[tt];
        }
    }
    __syncthreads();

    // ---- phase 3: y = M * Z; wave w -> row-tile w>>1, col-half w&1 ----
    f32x4 acc[4];
    #pragma unroll
    for (int nf = 0; nf < 4; ++nf)
        #pragma unroll
        for (int k = 0; k < 4; ++k) acc[nf][k] = 0.f;

    const int arow = (w >> 1) * 16 + n;
    const int nfb  = (w & 1) * 4;
    #pragma unroll
    for (int kt = 0; kt < 6; ++kt) {
        int c = kt * 4 + q;
        int csa = (c & ~7) | ((c & 7) ^ (arow & 7));
        short8 af = *(const short8*)&Ms[(arow * 24 + csa) * 8];
        #pragma unroll
        for (int j = 0; j < 4; ++j) {
            int col = (nfb + j) * 16 + n;
            int csb = (c & ~7) | ((c & 7) ^ (col & 7));
            short8 bfr = *(const short8*)&Zs[(col * 24 + csb) * 8];
            acc[j] = __builtin_amdgcn_mfma_f32_16x16x32_bf16(af, bfr, acc[j], 0, 0, 0);
        }
    }

    const float Dd = Dp[d];
    const int i0 = (w >> 1) * 16 + q * 4;
    #pragma unroll
    for (int j = 0; j < 4; ++j) {
        int col = (nfb + j) * 16 + n;
        int bb = col >> 5, ch = col & 31;
        int cx = (i0 >> 3) ^ (col & 7);
        const ushort* zp = (const ushort*)&Zs[(col * 24 + cx) * 8 + (i0 & 7)];
        ushort o[4];
        #pragma unroll
        for (int r = 0; r < 4; ++r)
            o[r] = f2bf(acc[j][r] + Dd * bf2f(zp[r]));
        *(uint2*)&yT[((size_t)d * BATCH + bb) * SEQ + ch * 64 + i0] = *(uint2*)o;
    }
}

// ---------------- k_gemm_ln v17: double-buffered Bs, one barrier per K-step (round-27) ----------------
__global__ __launch_bounds__(512) void k_gemm_ln(
    const __hip_bfloat16* __restrict__ yT, const __hip_bfloat16* __restrict__ Wbf,
    const float* __restrict__ x, const float* __restrict__ bout,
    const float* __restrict__ gamma, const float* __restrict__ beta,
    float* __restrict__ out)
{
    __shared__ short Af[32][520];
    __shared__ short Bs[2][512][32];
    __shared__ float red[8][32][2];
    __shared__ float stats[32][2];

    const int tid  = threadIdx.x;
    const int w    = tid >> 6;
    const int lane = tid & 63;
    const int q    = lane >> 4;
    const int m    = lane & 15;
    const int r0   = blockIdx.x * 32;
    const int bq   = r0 >> 11;
    const int l0   = r0 & 2047;

    {
        const int kdb = tid >> 3, lg = (tid & 7) * 4;
        uint2 u[8];
        #pragma unroll
        for (int j = 0; j < 8; ++j)
            u[j] = *(const uint2*)&yT[((size_t)(j * 64 + kdb) * BATCH + bq) * SEQ + l0 + lg];
        #pragma unroll
        for (int j = 0; j < 8; ++j) {
            int kd = j * 64 + kdb;
            Af[lg + 0][kd] = (short)(u[j].x & 0xffff);
            Af[lg + 1][kd] = (short)(u[j].x >> 16);
            Af[lg + 2][kd] = (short)(u[j].y & 0xffff);
            Af[lg + 3][kd] = (short)(u[j].y >> 16);
        }
    }

    short8 nb0, nb1, nb2, nb3;
    const int ob = tid >> 2, jb = tid & 3;
    const int js = (jb ^ (ob & 3)) * 8;
    #define LOADB(k0) { \
        nb0 = *(const short8*)(Wbf + (size_t)(ob      ) * DM + (k0) + jb * 8); \
        nb1 = *(const short8*)(Wbf + (size_t)(ob + 128) * DM + (k0) + jb * 8); \
        nb2 = *(const short8*)(Wbf + (size_t)(ob + 256) * DM + (k0) + jb * 8); \
        nb3 = *(const short8*)(Wbf + (size_t)(ob + 384) * DM + (k0) + jb * 8); }
    #define WRITEB(p) { \
        *(short8*)&Bs[p][ob      ][js] = nb0; \
        *(short8*)&Bs[p][ob + 128][js] = nb1; \
        *(short8*)&Bs[p][ob + 256][js] = nb2; \
        *(short8*)&Bs[p][ob + 384][js] = nb3; }

    LOADB(0);
    WRITEB(0);
    LOADB(32);
    __syncthreads();

    f32x4 acc[2][4];
    #pragma unroll
    for (int a = 0; a < 2; ++a)
        #pragma unroll
        for (int nn = 0; nn < 4; ++nn)
            #pragma unroll
            for (int k = 0; k < 4; ++k) acc[a][nn][k] = 0.f;

    int p = 0;
    for (int k = 0; k < 16; ++k) {
        if (k < 15) WRITEB(p ^ 1);
        if (k < 14) LOADB((k + 2) * 32);
        const int k0 = k * 32;
        short8 a0 = *(const short8*)&Af[m][k0 + q * 8];
        short8 a1 = *(const short8*)&Af[16 + m][k0 + q * 8];
        #pragma unroll
        for (int nf = 0; nf < 4; ++nf) {
            int o = w * 64 + nf * 16 + m;
            short8 bb = *(const short8*)&Bs[p][o][(q ^ (m & 3)) * 8];
            acc[0][nf] = __builtin_amdgcn_mfma_f32_16x16x32_bf16(a0, bb, acc[0][nf], 0, 0, 0);
            acc[1][nf] = __builtin_amdgcn_mfma_f32_16x16x32_bf16(a1, bb, acc[1][nf], 0, 0, 0);
        }
        __syncthreads();
        p ^= 1;
    }
    #undef LOADB
    #undef WRITEB

    float bo[4], ga[4], be[4];
    #pragma unroll
    for (int nf = 0; nf < 4; ++nf) {
        int o = w * 64 + nf * 16 + m;
        bo[nf] = bout[o]; ga[nf] = gamma[o]; be[nf] = beta[o];
    }

    float rs[2][4], rq[2][4];
    #pragma unroll
    for (int mf = 0; mf < 2; ++mf)
        #pragma unroll
        for (int i = 0; i < 4; ++i) { rs[mf][i] = 0.f; rq[mf][i] = 0.f; }

    #pragma unroll
    for (int mf = 0; mf < 2; ++mf)
        #pragma unroll
        for (int nf = 0; nf < 4; ++nf) {
            int o = w * 64 + nf * 16 + m;
            #pragma unroll
            for (int i = 0; i < 4; ++i) {
                int row = mf * 16 + q * 4 + i;
                float zv = acc[mf][nf][i] + bo[nf] + x[(size_t)(r0 + row) * DM + o];
                acc[mf][nf][i] = zv;
                rs[mf][i] += zv;
                rq[mf][i] += zv * zv;
            }
        }

    #pragma unroll
    for (int mask = 1; mask < 16; mask <<= 1) {
        #pragma unroll
        for (int mf = 0; mf < 2; ++mf)
            #pragma unroll
            for (int i = 0; i < 4; ++i) {
                rs[mf][i] += __shfl_xor(rs[mf][i], mask);
                rq[mf][i] += __shfl_xor(rq[mf][i], mask);
            }
    }
    if (m == 0) {
        #pragma unroll
        for (int mf = 0; mf < 2; ++mf)
            #pragma unroll
            for (int i = 0; i < 4; ++i) {
                int row = mf * 16 + q * 4 + i;
                red[w][row][0] = rs[mf][i];
                red[w][row][1] = rq[mf][i];
            }
    }
    __syncthreads();
    if (tid < 32) {
        float s = 0.f, sq = 0.f;
        #pragma unroll
        for (int ww = 0; ww < 8; ++ww) { s += red[ww][tid][0]; sq += red[ww][tid][1]; }
        float mu  = s * (1.f / DM);
        float var = sq * (1.f / DM) - mu * mu;
        stats[tid][0] = mu;
        stats[tid][1] = 1.f / sqrtf(var + LN_EPS);
    }
    __syncthreads();

    #pragma unroll
    for (int mf = 0; mf < 2; ++mf)
        #pragma unroll
        for (int i = 0; i < 4; ++i) {
            int row = mf * 16 + q * 4 + i;
            float mu = stats[row][0], rstd = stats[row][1];
            #pragma unroll
            for (int nf = 0; nf < 4; ++nf) {
                int o = w * 64 + nf * 16 + m;
                out[(size_t)(r0 + row) * DM + o] =
                    ga[nf] * (acc[mf][nf][i] - mu) * rstd + be[nf];
            }
        }
}

// ---------------- launcher ----------------
// ATTRIBUTION ROUND: k_prep launched 4x (idempotent). t_prep = (T - 48.4)/3.
// ssm reverted to v3 (v4 neutral, more complex). Revert prep to 1x next round.
extern "C" void kernel_launch(void* const* d_in, const int* in_sizes, int n_in,
                              void* d_out, int out_size, void* d_ws, size_t ws_size,
                              hipStream_t stream)
{
    const float* x    = (const float*)d_in[0];
    const float* logA = (const float*)d_in[1];
    const float* Aim  = (const float*)d_in[2];
    const float* Bp   = (const float*)d_in[3];
    const float* Cp   = (const float*)d_in[4];
    const float* Dp   = (const float*)d_in[5];
    const float* W    = (const float*)d_in[6];
    const float* bo   = (const float*)d_in[7];
    const float* ga   = (const float*)d_in[8];
    const float* be   = (const float*)d_in[9];

    char* ws = (char*)d_ws;
    __hip_bfloat16* Wbf = (__hip_bfloat16*)ws;                   // 512 KiB @ 0
    __hip_bfloat16* xT  = (__hip_bfloat16*)(ws + (3u << 20));    // 8 MiB    @ 3M
    __hip_bfloat16* yT  = (__hip_bfloat16*)(ws + (41u << 20));   // 8 MiB    @ 41M

    k_prep   <<<3072, 256, 0, stream>>>(x, W, xT, Wbf);
    k_prep   <<<3072, 256, 0, stream>>>(x, W, xT, Wbf);
    k_prep   <<<3072, 256, 0, stream>>>(x, W, xT, Wbf);
    k_prep   <<<3072, 256, 0, stream>>>(x, W, xT, Wbf);
    k_ssm    <<<DM, 512, 0, stream>>>(logA, Aim, Bp, Cp, xT, Dp, yT);
    k_gemm_ln<<<(BATCH * SEQ) / 32, 512, 0, stream>>>(yT, Wbf, x, bo, ga, be, (float*)d_out);
}

// Round 30
// 48.984 us; speedup vs baseline: 1.2230x; 1.2230x over previous
//
#include <hip/hip_runtime.h>
#include <hip/hip_bf16.h>
#include <stdint.h>
#include <stddef.h>

#define BATCH 4
#define SEQ   2048
#define DM    512
#define NST   64
#define LN_EPS 1e-5f
#define NCH   32
#define KDIM  192

typedef __attribute__((ext_vector_type(8))) short short8;
typedef __attribute__((ext_vector_type(4))) float f32x4;

__device__ __forceinline__ ushort f2bf(float f) {
    __hip_bfloat16 h = __float2bfloat16(f);
    return *(ushort*)&h;
}
__device__ __forceinline__ float bf2f(ushort u) {
    __hip_bfloat16 h = *(__hip_bfloat16*)&u;
    return __bfloat162float(h);
}

// ---------------- k_prep: x-transpose + W-convert ----------------
__global__ __launch_bounds__(256) void k_prep(
    const float* __restrict__ x, const float* __restrict__ W,
    __hip_bfloat16* __restrict__ xT, __hip_bfloat16* __restrict__ Wbf)
{
    __shared__ float smem[64][33];
    const int tid = threadIdx.x;
    const int bid = blockIdx.x;

    if (bid < 2048) {
        const int dt = bid & 15, lt = (bid >> 4) & 31, b = bid >> 9;
        const int l0 = lt * 64, d0 = dt * 32;
        const int dd = tid & 31, lr = tid >> 5;
        #pragma unroll
        for (int it = 0; it < 8; ++it) {
            int ll = it * 8 + lr;
            smem[ll][dd] = x[((size_t)b * SEQ + l0 + ll) * DM + d0 + dd];
        }
        __syncthreads();
        const int dw = tid >> 3, lg = (tid & 7) * 8;
        ushort pk[8];
        #pragma unroll
        for (int i = 0; i < 8; ++i) pk[i] = f2bf(smem[lg + i][dw]);
        *(short8*)&xT[((size_t)(d0 + dw) * BATCH + b) * SEQ + l0 + lg] = *(short8*)pk;
    } else {
        int i = (bid - 2048) * 256 + tid;
        if (i < DM * DM) Wbf[i] = __float2bfloat16(W[i]);
    }
}

// ---------------- k_ssm v3: 512 threads, in-block G/M build + 3 MFMA phases (round-26 proven) ----------------
__global__ __launch_bounds__(512) void k_ssm(
    const float* __restrict__ logA, const float* __restrict__ Aim,
    const float* __restrict__ Bp, const float* __restrict__ Cp,
    const __hip_bfloat16* __restrict__ xT, const float* __restrict__ Dp,
    __hip_bfloat16* __restrict__ yT)
{
    __shared__ short Zs[128 * 24 * 8];             // 48K: x chunks 0-7, carry chunks 8-23
    __shared__ __align__(16) char Rgn[128 * 129 * 4];   // 64.5K union: Gs / Us / Ms
    __shared__ float Klds[64];
    __shared__ float2 e64s[64];
    short* Gs = (short*)Rgn;
    float (*Us)[129] = (float(*)[129])Rgn;
    short* Ms = (short*)Rgn;

    const int tid = threadIdx.x;
    const int d = blockIdx.x;
    const int w = tid >> 6, lane = tid & 63;
    const int q = lane >> 4, n = lane & 15;

    // ---- issue Zs x-part loads early (land during G build) ----
    short8 xr[2];
    #pragma unroll
    for (int it = 0; it < 2; ++it) {
        int id = it * 512 + tid;
        int col = id >> 3, ck = id & 7;
        int bb = col >> 5, ch = col & 31;
        xr[it] = *(const short8*)&xT[((size_t)d * BATCH + bb) * SEQ + ch * 64 + ck * 8];
    }

    // ---- build G rows (2s,2s+1) chunk w, K partials, carry entries; wave j covers t in [8j,8j+8) ----
    uint mca[8];
    {
        const int s = lane;
        const int i = d * NST + s;
        float aa  = expf(logA[i]);
        float wim = Aim[i];
        float mag = expf(-aa);
        float er = mag * cosf(wim), ei = mag * sinf(wim);
        float Br = Bp[2*i], Bi = Bp[2*i+1];
        float Cr = Cp[2*i], Ci = Cp[2*i+1];
        float CBr = Cr*Br + Ci*Bi;
        float CBi = Cr*Bi - Ci*Br;

        float e2r = er*er - ei*ei,   e2i = 2.f*er*ei;
        float e4r = e2r*e2r - e2i*e2i, e4i = 2.f*e2r*e2i;
        float e8r = e4r*e4r - e4i*e4i, e8i = 2.f*e4r*e4i;       // eA^8
        float ar, ai;
        if (w == 0)      { ar = 1.f;  ai = 0.f; }
        else if (w == 1) { ar = e8r;  ai = e8i; }
        else {
            float e16r = e8r*e8r - e8i*e8i, e16i = 2.f*e8r*e8i;
            if (w == 2)      { ar = e16r; ai = e16i; }
            else if (w == 3) { ar = e16r*e8r - e16i*e8i;  ai = e16r*e8i + e16i*e8r; }
            else {
                float e32r = e16r*e16r - e16i*e16i, e32i = 2.f*e16r*e16i;
                if (w == 4)      { ar = e32r; ai = e32i; }
                else if (w == 5) { ar = e32r*e8r - e32i*e8i;   ai = e32r*e8i + e32i*e8r; }
                else if (w == 6) { ar = e32r*e16r - e32i*e16i; ai = e32r*e16i + e32i*e16r; }
                else {
                    float e48r = e32r*e16r - e32i*e16i, e48i = e32r*e16i + e32i*e16r;
                    ar = e48r*e8r - e48i*e8i;  ai = e48r*e8i + e48i*e8r;   // eA^56
                }
            }
        }
        float prr = CBr*ar - CBi*ai;
        float pii = CBr*ai + CBi*ar;

        float kb[8];
        ushort gR[8], gI[8];
        #pragma unroll
        for (int tt = 0; tt < 8; ++tt) {
            kb[tt] = prr;
            gR[tt] = f2bf(prr);
            gI[tt] = f2bf(pii);
            float npr = er*prr - ei*pii, npi = er*pii + ei*prr;  prr = npr; pii = npi;
            float nar = er*ar - ei*ai,   nai = er*ai + ei*ar;    ar = nar; ai = nai;
            mca[tt] = (uint)f2bf(ar) | ((uint)f2bf(-ai) << 16);
        }
        if (w == 7) e64s[s] = make_float2(ar, ai);

        short8 v;
        int row = 2 * s;
        #pragma unroll
        for (int e = 0; e < 8; ++e) v[e] = (short)gR[e];
        { int cs = w ^ (row & 7); *(short8*)&Gs[(row * 8 + cs) * 8] = v; }
        row = 2 * s + 1;
        #pragma unroll
        for (int e = 0; e < 8; ++e) v[e] = (short)gI[e];
        { int cs = w ^ (row & 7); *(short8*)&Gs[(row * 8 + cs) * 8] = v; }

        #pragma unroll
        for (int tt = 0; tt < 8; ++tt) {
            float v2 = kb[tt];
            #pragma unroll
            for (int mask = 1; mask < 64; mask <<= 1) v2 += __shfl_xor(v2, mask);
            if (lane == 0) Klds[8 * w + tt] = v2;
        }
    }

    // ---- write Zs x-part from prefetched regs ----
    #pragma unroll
    for (int it = 0; it < 2; ++it) {
        int id = it * 512 + tid;
        int col = id >> 3, ck = id & 7;
        int cs = ck ^ (col & 7);
        *(short8*)&Zs[(col * 24 + cs) * 8] = xr[it];
    }
    __syncthreads();

    // ---- phase 1: U = G * X (wave w owns rows 16w..16w+15) ----
    f32x4 acc1[8];
    {
        #pragma unroll
        for (int nf = 0; nf < 8; ++nf)
            #pragma unroll
            for (int k = 0; k < 4; ++k) acc1[nf][k] = 0.f;

        const int arow = w * 16 + n;
        #pragma unroll
        for (int kt = 0; kt < 2; ++kt) {
            int c = kt * 4 + q;
            int csa = c ^ (arow & 7);
            short8 af = *(const short8*)&Gs[(arow * 8 + csa) * 8];
            #pragma unroll
            for (int nf = 0; nf < 8; ++nf) {
                int col = nf * 16 + n;
                int csb = c ^ (col & 7);
                short8 bf = *(const short8*)&Zs[(col * 24 + csb) * 8];
                acc1[nf] = __builtin_amdgcn_mfma_f32_16x16x32_bf16(af, bf, acc1[nf], 0, 0, 0);
            }
        }
    }
    __syncthreads();

    {
        const int r0w = w * 16 + q * 4;
        #pragma unroll
        for (int nf = 0; nf < 8; ++nf) {
            int col = nf * 16 + n;
            #pragma unroll
            for (int r = 0; r < 4; ++r) Us[r0w + r][col] = acc1[nf][r];
        }
    }
    __syncthreads();

    // ---- phase 2: carry combine (tid<256) ----
    if (tid < 256) {
        const int bb = tid >> 6, s = tid & 63;
        const int st = s >> 2, so = (s & 3) * 2;
        float2 a64 = e64s[s];
        const float er = a64.x, ei = a64.y;
        {
            int col = bb * 32 + 31;
            int c = 8 + st, cs = (c & ~7) | ((c & 7) ^ (col & 7));
            *(uint*)&Zs[(col * 24 + cs) * 8 + so] = 0u;
        }
        float gr = Us[2 * s][bb * 32 + 31], gi = Us[2 * s + 1][bb * 32 + 31];
        {
            int col = bb * 32 + 30;
            int c = 8 + st, cs = (c & ~7) | ((c & 7) ^ (col & 7));
            *(uint*)&Zs[(col * 24 + cs) * 8 + so] = (uint)f2bf(gr) | ((uint)f2bf(gi) << 16);
        }
        #pragma unroll 6
        for (int ch = 30; ch >= 1; --ch) {
            float ur = Us[2 * s][bb * 32 + ch], ui = Us[2 * s + 1][bb * 32 + ch];
            float nr = ur + er * gr - ei * gi;
            float ni = ui + er * gi + ei * gr;
            gr = nr; gi = ni;
            int col = bb * 32 + ch - 1;
            int c = 8 + st, cs = (c & ~7) | ((c & 7) ^ (col & 7));
            *(uint*)&Zs[(col * 24 + cs) * 8 + so] = (uint)f2bf(gr) | ((uint)f2bf(gi) << 16);
        }
    }
    __syncthreads();

    // ---- build Ms ----
    {
        {
            int id = tid;
            int row = id >> 3, c = id & 7;
            short8 v;
            #pragma unroll
            for (int e = 0; e < 8; ++e) {
                int col = c * 8 + e;
                float kv = (col >= row) ? Klds[col - row] : 0.f;
                v[e] = (short)f2bf(kv);
            }
            int cs = c ^ (row & 7);
            *(short8*)&Ms[(row * 24 + cs) * 8] = v;
        }
        const int s = lane;
        const int cc = 8 + (s >> 2);
        const int soff = 2 * (s & 3);
        #pragma unroll
        for (int tt = 0; tt < 8; ++tt) {
            int row = 63 - (8 * w + tt);
            int cs = (cc & ~7) | ((cc & 7) ^ (row & 7));
            *(uint*)&Ms[(row * 24 + cs) * 8 + soff] = mca[tt];
        }
    }
    __syncthreads();

    // ---- phase 3: y = M * Z; wave w -> row-tile w>>1, col-half w&1 ----
    f32x4 acc[4];
    #pragma unroll
    for (int nf = 0; nf < 4; ++nf)
        #pragma unroll
        for (int k = 0; k < 4; ++k) acc[nf][k] = 0.f;

    const int arow = (w >> 1) * 16 + n;
    const int nfb  = (w & 1) * 4;
    #pragma unroll
    for (int kt = 0; kt < 6; ++kt) {
        int c = kt * 4 + q;
        int csa = (c & ~7) | ((c & 7) ^ (arow & 7));
        short8 af = *(const short8*)&Ms[(arow * 24 + csa) * 8];
        #pragma unroll
        for (int j = 0; j < 4; ++j) {
            int col = (nfb + j) * 16 + n;
            int csb = (c & ~7) | ((c & 7) ^ (col & 7));
            short8 bfr = *(const short8*)&Zs[(col * 24 + csb) * 8];
            acc[j] = __builtin_amdgcn_mfma_f32_16x16x32_bf16(af, bfr, acc[j], 0, 0, 0);
        }
    }

    const float Dd = Dp[d];
    const int i0 = (w >> 1) * 16 + q * 4;
    #pragma unroll
    for (int j = 0; j < 4; ++j) {
        int col = (nfb + j) * 16 + n;
        int bb = col >> 5, ch = col & 31;
        int cx = (i0 >> 3) ^ (col & 7);
        const ushort* zp = (const ushort*)&Zs[(col * 24 + cx) * 8 + (i0 & 7)];
        ushort o[4];
        #pragma unroll
        for (int r = 0; r < 4; ++r)
            o[r] = f2bf(acc[j][r] + Dd * bf2f(zp[r]));
        *(uint2*)&yT[((size_t)d * BATCH + bb) * SEQ + ch * 64 + i0] = *(uint2*)o;
    }
}

// ---------------- k_gemm_ln v18: Bs rows padded to 36 shorts (bank de-aliasing) ----------------
// Round-29 audit: v17's Bs row stride (32 shorts = 16 dwords == 16 mod 32 banks) aliases
// rows with period 2; the 2-bit XOR swizzle left B-frag reads 4-8-way bank conflicted
// (128 b128 reads/thread -> the ~6us hidden LDS serialization; why v15/v16/v17 were null).
// Stride 36 shorts = 18 dwords: m*18 mod 32 distinct for all 16 m -> ~2-way (free).
// XOR swizzle dropped (write [o][jb*8], read [o][q*8]).
__global__ __launch_bounds__(512) void k_gemm_ln(
    const __hip_bfloat16* __restrict__ yT, const __hip_bfloat16* __restrict__ Wbf,
    const float* __restrict__ x, const float* __restrict__ bout,
    const float* __restrict__ gamma, const float* __restrict__ beta,
    float* __restrict__ out)
{
    __shared__ short Af[32][520];
    __shared__ short Bs[2][512][36];   // padded rows: 18 dwords -> all 16 row-lanes on distinct banks
    __shared__ float red[8][32][2];
    __shared__ float stats[32][2];

    const int tid  = threadIdx.x;
    const int w    = tid >> 6;
    const int lane = tid & 63;
    const int q    = lane >> 4;
    const int m    = lane & 15;
    const int r0   = blockIdx.x * 32;
    const int bq   = r0 >> 11;
    const int l0   = r0 & 2047;

    // ---- one-time A panel from yT[d][b][l] ----
    {
        const int kdb = tid >> 3, lg = (tid & 7) * 4;
        uint2 u[8];
        #pragma unroll
        for (int j = 0; j < 8; ++j)
            u[j] = *(const uint2*)&yT[((size_t)(j * 64 + kdb) * BATCH + bq) * SEQ + l0 + lg];
        #pragma unroll
        for (int j = 0; j < 8; ++j) {
            int kd = j * 64 + kdb;
            Af[lg + 0][kd] = (short)(u[j].x & 0xffff);
            Af[lg + 1][kd] = (short)(u[j].x >> 16);
            Af[lg + 2][kd] = (short)(u[j].y & 0xffff);
            Af[lg + 3][kd] = (short)(u[j].y >> 16);
        }
    }

    // ---- B tile staging: 512 o x 32 k per step; 4 x 16B per thread ----
    short8 nb0, nb1, nb2, nb3;
    const int ob = tid >> 2, jb = tid & 3;
    const int js = jb * 8;
    #define LOADB(k0) { \
        nb0 = *(const short8*)(Wbf + (size_t)(ob      ) * DM + (k0) + jb * 8); \
        nb1 = *(const short8*)(Wbf + (size_t)(ob + 128) * DM + (k0) + jb * 8); \
        nb2 = *(const short8*)(Wbf + (size_t)(ob + 256) * DM + (k0) + jb * 8); \
        nb3 = *(const short8*)(Wbf + (size_t)(ob + 384) * DM + (k0) + jb * 8); }
    #define WRITEB(p) { \
        *(short8*)&Bs[p][ob      ][js] = nb0; \
        *(short8*)&Bs[p][ob + 128][js] = nb1; \
        *(short8*)&Bs[p][ob + 256][js] = nb2; \
        *(short8*)&Bs[p][ob + 384][js] = nb3; }

    LOADB(0);
    WRITEB(0);
    LOADB(32);
    __syncthreads();

    f32x4 acc[2][4];
    #pragma unroll
    for (int a = 0; a < 2; ++a)
        #pragma unroll
        for (int nn = 0; nn < 4; ++nn)
            #pragma unroll
            for (int k = 0; k < 4; ++k) acc[a][nn][k] = 0.f;

    int p = 0;
    for (int k = 0; k < 16; ++k) {
        if (k < 15) WRITEB(p ^ 1);
        if (k < 14) LOADB((k + 2) * 32);
        const int k0 = k * 32;
        short8 a0 = *(const short8*)&Af[m][k0 + q * 8];
        short8 a1 = *(const short8*)&Af[16 + m][k0 + q * 8];
        #pragma unroll
        for (int nf = 0; nf < 4; ++nf) {
            int o = w * 64 + nf * 16 + m;
            short8 bb = *(const short8*)&Bs[p][o][q * 8];
            acc[0][nf] = __builtin_amdgcn_mfma_f32_16x16x32_bf16(a0, bb, acc[0][nf], 0, 0, 0);
            acc[1][nf] = __builtin_amdgcn_mfma_f32_16x16x32_bf16(a1, bb, acc[1][nf], 0, 0, 0);
        }
        __syncthreads();
        p ^= 1;
    }
    #undef LOADB
    #undef WRITEB

    // ---- epilogue: +bias, +x residual, row mean/var, normalize ----
    float bo[4], ga[4], be[4];
    #pragma unroll
    for (int nf = 0; nf < 4; ++nf) {
        int o = w * 64 + nf * 16 + m;
        bo[nf] = bout[o]; ga[nf] = gamma[o]; be[nf] = beta[o];
    }

    float rs[2][4], rq[2][4];
    #pragma unroll
    for (int mf = 0; mf < 2; ++mf)
        #pragma unroll
        for (int i = 0; i < 4; ++i) { rs[mf][i] = 0.f; rq[mf][i] = 0.f; }

    #pragma unroll
    for (int mf = 0; mf < 2; ++mf)
        #pragma unroll
        for (int nf = 0; nf < 4; ++nf) {
            int o = w * 64 + nf * 16 + m;
            #pragma unroll
            for (int i = 0; i < 4; ++i) {
                int row = mf * 16 + q * 4 + i;
                float zv = acc[mf][nf][i] + bo[nf] + x[(size_t)(r0 + row) * DM + o];
                acc[mf][nf][i] = zv;
                rs[mf][i] += zv;
                rq[mf][i] += zv * zv;
            }
        }

    #pragma unroll
    for (int mask = 1; mask < 16; mask <<= 1) {
        #pragma unroll
        for (int mf = 0; mf < 2; ++mf)
            #pragma unroll
            for (int i = 0; i < 4; ++i) {
                rs[mf][i] += __shfl_xor(rs[mf][i], mask);
                rq[mf][i] += __shfl_xor(rq[mf][i], mask);
            }
    }
    if (m == 0) {
        #pragma unroll
        for (int mf = 0; mf < 2; ++mf)
            #pragma unroll
            for (int i = 0; i < 4; ++i) {
                int row = mf * 16 + q * 4 + i;
                red[w][row][0] = rs[mf][i];
                red[w][row][1] = rq[mf][i];
            }
    }
    __syncthreads();
    if (tid < 32) {
        float s = 0.f, sq = 0.f;
        #pragma unroll
        for (int ww = 0; ww < 8; ++ww) { s += red[ww][tid][0]; sq += red[ww][tid][1]; }
        float mu  = s * (1.f / DM);
        float var = sq * (1.f / DM) - mu * mu;
        stats[tid][0] = mu;
        stats[tid][1] = 1.f / sqrtf(var + LN_EPS);
    }
    __syncthreads();

    #pragma unroll
    for (int mf = 0; mf < 2; ++mf)
        #pragma unroll
        for (int i = 0; i < 4; ++i) {
            int row = mf * 16 + q * 4 + i;
            float mu = stats[row][0], rstd = stats[row][1];
            #pragma unroll
            for (int nf = 0; nf < 4; ++nf) {
                int o = w * 64 + nf * 16 + m;
                out[(size_t)(r0 + row) * DM + o] =
                    ga[nf] * (acc[mf][nf][i] - mu) * rstd + be[nf];
            }
        }
}

// ---------------- launcher ----------------
extern "C" void kernel_launch(void* const* d_in, const int* in_sizes, int n_in,
                              void* d_out, int out_size, void* d_ws, size_t ws_size,
                              hipStream_t stream)
{
    const float* x    = (const float*)d_in[0];
    const float* logA = (const float*)d_in[1];
    const float* Aim  = (const float*)d_in[2];
    const float* Bp   = (const float*)d_in[3];
    const float* Cp   = (const float*)d_in[4];
    const float* Dp   = (const float*)d_in[5];
    const float* W    = (const float*)d_in[6];
    const float* bo   = (const float*)d_in[7];
    const float* ga   = (const float*)d_in[8];
    const float* be   = (const float*)d_in[9];

    char* ws = (char*)d_ws;
    __hip_bfloat16* Wbf = (__hip_bfloat16*)ws;                   // 512 KiB @ 0
    __hip_bfloat16* xT  = (__hip_bfloat16*)(ws + (3u << 20));    // 8 MiB    @ 3M
    __hip_bfloat16* yT  = (__hip_bfloat16*)(ws + (41u << 20));   // 8 MiB    @ 41M

    k_prep   <<<3072, 256, 0, stream>>>(x, W, xT, Wbf);
    k_ssm    <<<DM, 512, 0, stream>>>(logA, Aim, Bp, Cp, xT, Dp, yT);
    k_gemm_ln<<<(BATCH * SEQ) / 32, 512, 0, stream>>>(yT, Wbf, x, bo, ga, be, (float*)d_out);
}

// Round 31
// 48.439 us; speedup vs baseline: 1.2368x; 1.0113x over previous
//
#include <hip/hip_runtime.h>
#include <hip/hip_bf16.h>
#include <stdint.h>
#include <stddef.h>

#define BATCH 4
#define SEQ   2048
#define DM    512
#define NST   64
#define LN_EPS 1e-5f
#define NCH   32
#define KDIM  192

typedef __attribute__((ext_vector_type(8))) short short8;
typedef __attribute__((ext_vector_type(4))) float f32x4;

__device__ __forceinline__ ushort f2bf(float f) {
    __hip_bfloat16 h = __float2bfloat16(f);
    return *(ushort*)&h;
}
__device__ __forceinline__ float bf2f(ushort u) {
    __hip_bfloat16 h = *(__hip_bfloat16*)&u;
    return __bfloat162float(h);
}

// ---------------- k_prep: x-transpose + W-convert (measured at HBM roofline: 3.8us) ----------------
__global__ __launch_bounds__(256) void k_prep(
    const float* __restrict__ x, const float* __restrict__ W,
    __hip_bfloat16* __restrict__ xT, __hip_bfloat16* __restrict__ Wbf)
{
    __shared__ float smem[64][33];
    const int tid = threadIdx.x;
    const int bid = blockIdx.x;

    if (bid < 2048) {
        const int dt = bid & 15, lt = (bid >> 4) & 31, b = bid >> 9;
        const int l0 = lt * 64, d0 = dt * 32;
        const int dd = tid & 31, lr = tid >> 5;
        #pragma unroll
        for (int it = 0; it < 8; ++it) {
            int ll = it * 8 + lr;
            smem[ll][dd] = x[((size_t)b * SEQ + l0 + ll) * DM + d0 + dd];
        }
        __syncthreads();
        const int dw = tid >> 3, lg = (tid & 7) * 8;
        ushort pk[8];
        #pragma unroll
        for (int i = 0; i < 8; ++i) pk[i] = f2bf(smem[lg + i][dw]);
        *(short8*)&xT[((size_t)(d0 + dw) * BATCH + b) * SEQ + l0 + lg] = *(short8*)pk;
    } else {
        int i = (bid - 2048) * 256 + tid;
        if (i < DM * DM) Wbf[i] = __float2bfloat16(W[i]);
    }
}

// ---------------- k_ssm v3: 512 threads, in-block G/M build + 3 MFMA phases (round-26/27 best) ----------------
__global__ __launch_bounds__(512) void k_ssm(
    const float* __restrict__ logA, const float* __restrict__ Aim,
    const float* __restrict__ Bp, const float* __restrict__ Cp,
    const __hip_bfloat16* __restrict__ xT, const float* __restrict__ Dp,
    __hip_bfloat16* __restrict__ yT)
{
    __shared__ short Zs[128 * 24 * 8];             // 48K: x chunks 0-7, carry chunks 8-23
    __shared__ __align__(16) char Rgn[128 * 129 * 4];   // 64.5K union: Gs / Us / Ms
    __shared__ float Klds[64];
    __shared__ float2 e64s[64];
    short* Gs = (short*)Rgn;
    float (*Us)[129] = (float(*)[129])Rgn;
    short* Ms = (short*)Rgn;

    const int tid = threadIdx.x;
    const int d = blockIdx.x;
    const int w = tid >> 6, lane = tid & 63;
    const int q = lane >> 4, n = lane & 15;

    // ---- issue Zs x-part loads early (land during G build) ----
    short8 xr[2];
    #pragma unroll
    for (int it = 0; it < 2; ++it) {
        int id = it * 512 + tid;
        int col = id >> 3, ck = id & 7;
        int bb = col >> 5, ch = col & 31;
        xr[it] = *(const short8*)&xT[((size_t)d * BATCH + bb) * SEQ + ch * 64 + ck * 8];
    }

    // ---- build G rows (2s,2s+1) chunk w, K partials, carry entries; wave j covers t in [8j,8j+8) ----
    uint mca[8];
    {
        const int s = lane;
        const int i = d * NST + s;
        float aa  = expf(logA[i]);
        float wim = Aim[i];
        float mag = expf(-aa);
        float er = mag * cosf(wim), ei = mag * sinf(wim);
        float Br = Bp[2*i], Bi = Bp[2*i+1];
        float Cr = Cp[2*i], Ci = Cp[2*i+1];
        float CBr = Cr*Br + Ci*Bi;
        float CBi = Cr*Bi - Ci*Br;

        float e2r = er*er - ei*ei,   e2i = 2.f*er*ei;
        float e4r = e2r*e2r - e2i*e2i, e4i = 2.f*e2r*e2i;
        float e8r = e4r*e4r - e4i*e4i, e8i = 2.f*e4r*e4i;       // eA^8
        float ar, ai;
        if (w == 0)      { ar = 1.f;  ai = 0.f; }
        else if (w == 1) { ar = e8r;  ai = e8i; }
        else {
            float e16r = e8r*e8r - e8i*e8i, e16i = 2.f*e8r*e8i;
            if (w == 2)      { ar = e16r; ai = e16i; }
            else if (w == 3) { ar = e16r*e8r - e16i*e8i;  ai = e16r*e8i + e16i*e8r; }
            else {
                float e32r = e16r*e16r - e16i*e16i, e32i = 2.f*e16r*e16i;
                if (w == 4)      { ar = e32r; ai = e32i; }
                else if (w == 5) { ar = e32r*e8r - e32i*e8i;   ai = e32r*e8i + e32i*e8r; }
                else if (w == 6) { ar = e32r*e16r - e32i*e16i; ai = e32r*e16i + e32i*e16r; }
                else {
                    float e48r = e32r*e16r - e32i*e16i, e48i = e32r*e16i + e32i*e16r;
                    ar = e48r*e8r - e48i*e8i;  ai = e48r*e8i + e48i*e8r;   // eA^56
                }
            }
        }
        float prr = CBr*ar - CBi*ai;
        float pii = CBr*ai + CBi*ar;

        float kb[8];
        ushort gR[8], gI[8];
        #pragma unroll
        for (int tt = 0; tt < 8; ++tt) {
            kb[tt] = prr;
            gR[tt] = f2bf(prr);
            gI[tt] = f2bf(pii);
            float npr = er*prr - ei*pii, npi = er*pii + ei*prr;  prr = npr; pii = npi;
            float nar = er*ar - ei*ai,   nai = er*ai + ei*ar;    ar = nar; ai = nai;
            mca[tt] = (uint)f2bf(ar) | ((uint)f2bf(-ai) << 16);
        }
        if (w == 7) e64s[s] = make_float2(ar, ai);

        short8 v;
        int row = 2 * s;
        #pragma unroll
        for (int e = 0; e < 8; ++e) v[e] = (short)gR[e];
        { int cs = w ^ (row & 7); *(short8*)&Gs[(row * 8 + cs) * 8] = v; }
        row = 2 * s + 1;
        #pragma unroll
        for (int e = 0; e < 8; ++e) v[e] = (short)gI[e];
        { int cs = w ^ (row & 7); *(short8*)&Gs[(row * 8 + cs) * 8] = v; }

        #pragma unroll
        for (int tt = 0; tt < 8; ++tt) {
            float v2 = kb[tt];
            #pragma unroll
            for (int mask = 1; mask < 64; mask <<= 1) v2 += __shfl_xor(v2, mask);
            if (lane == 0) Klds[8 * w + tt] = v2;
        }
    }

    // ---- write Zs x-part from prefetched regs ----
    #pragma unroll
    for (int it = 0; it < 2; ++it) {
        int id = it * 512 + tid;
        int col = id >> 3, ck = id & 7;
        int cs = ck ^ (col & 7);
        *(short8*)&Zs[(col * 24 + cs) * 8] = xr[it];
    }
    __syncthreads();

    // ---- phase 1: U = G * X (wave w owns rows 16w..16w+15) ----
    f32x4 acc1[8];
    {
        #pragma unroll
        for (int nf = 0; nf < 8; ++nf)
            #pragma unroll
            for (int k = 0; k < 4; ++k) acc1[nf][k] = 0.f;

        const int arow = w * 16 + n;
        #pragma unroll
        for (int kt = 0; kt < 2; ++kt) {
            int c = kt * 4 + q;
            int csa = c ^ (arow & 7);
            short8 af = *(const short8*)&Gs[(arow * 8 + csa) * 8];
            #pragma unroll
            for (int nf = 0; nf < 8; ++nf) {
                int col = nf * 16 + n;
                int csb = c ^ (col & 7);
                short8 bf = *(const short8*)&Zs[(col * 24 + csb) * 8];
                acc1[nf] = __builtin_amdgcn_mfma_f32_16x16x32_bf16(af, bf, acc1[nf], 0, 0, 0);
            }
        }
    }
    __syncthreads();

    {
        const int r0w = w * 16 + q * 4;
        #pragma unroll
        for (int nf = 0; nf < 8; ++nf) {
            int col = nf * 16 + n;
            #pragma unroll
            for (int r = 0; r < 4; ++r) Us[r0w + r][col] = acc1[nf][r];
        }
    }
    __syncthreads();

    // ---- phase 2: carry combine (tid<256) ----
    if (tid < 256) {
        const int bb = tid >> 6, s = tid & 63;
        const int st = s >> 2, so = (s & 3) * 2;
        float2 a64 = e64s[s];
        const float er = a64.x, ei = a64.y;
        {
            int col = bb * 32 + 31;
            int c = 8 + st, cs = (c & ~7) | ((c & 7) ^ (col & 7));
            *(uint*)&Zs[(col * 24 + cs) * 8 + so] = 0u;
        }
        float gr = Us[2 * s][bb * 32 + 31], gi = Us[2 * s + 1][bb * 32 + 31];
        {
            int col = bb * 32 + 30;
            int c = 8 + st, cs = (c & ~7) | ((c & 7) ^ (col & 7));
            *(uint*)&Zs[(col * 24 + cs) * 8 + so] = (uint)f2bf(gr) | ((uint)f2bf(gi) << 16);
        }
        #pragma unroll 6
        for (int ch = 30; ch >= 1; --ch) {
            float ur = Us[2 * s][bb * 32 + ch], ui = Us[2 * s + 1][bb * 32 + ch];
            float nr = ur + er * gr - ei * gi;
            float ni = ui + er * gi + ei * gr;
            gr = nr; gi = ni;
            int col = bb * 32 + ch - 1;
            int c = 8 + st, cs = (c & ~7) | ((c & 7) ^ (col & 7));
            *(uint*)&Zs[(col * 24 + cs) * 8 + so] = (uint)f2bf(gr) | ((uint)f2bf(gi) << 16);
        }
    }
    __syncthreads();

    // ---- build Ms ----
    {
        {
            int id = tid;
            int row = id >> 3, c = id & 7;
            short8 v;
            #pragma unroll
            for (int e = 0; e < 8; ++e) {
                int col = c * 8 + e;
                float kv = (col >= row) ? Klds[col - row] : 0.f;
                v[e] = (short)f2bf(kv);
            }
            int cs = c ^ (row & 7);
            *(short8*)&Ms[(row * 24 + cs) * 8] = v;
        }
        const int s = lane;
        const int cc = 8 + (s >> 2);
        const int soff = 2 * (s & 3);
        #pragma unroll
        for (int tt = 0; tt < 8; ++tt) {
            int row = 63 - (8 * w + tt);
            int cs = (cc & ~7) | ((cc & 7) ^ (row & 7));
            *(uint*)&Ms[(row * 24 + cs) * 8 + soff] = mca[tt];
        }
    }
    __syncthreads();

    // ---- phase 3: y = M * Z; wave w -> row-tile w>>1, col-half w&1 ----
    f32x4 acc[4];
    #pragma unroll
    for (int nf = 0; nf < 4; ++nf)
        #pragma unroll
        for (int k = 0; k < 4; ++k) acc[nf][k] = 0.f;

    const int arow = (w >> 1) * 16 + n;
    const int nfb  = (w & 1) * 4;
    #pragma unroll
    for (int kt = 0; kt < 6; ++kt) {
        int c = kt * 4 + q;
        int csa = (c & ~7) | ((c & 7) ^ (arow & 7));
        short8 af = *(const short8*)&Ms[(arow * 24 + csa) * 8];
        #pragma unroll
        for (int j = 0; j < 4; ++j) {
            int col = (nfb + j) * 16 + n;
            int csb = (c & ~7) | ((c & 7) ^ (col & 7));
            short8 bfr = *(const short8*)&Zs[(col * 24 + csb) * 8];
            acc[j] = __builtin_amdgcn_mfma_f32_16x16x32_bf16(af, bfr, acc[j], 0, 0, 0);
        }
    }

    const float Dd = Dp[d];
    const int i0 = (w >> 1) * 16 + q * 4;
    #pragma unroll
    for (int j = 0; j < 4; ++j) {
        int col = (nfb + j) * 16 + n;
        int bb = col >> 5, ch = col & 31;
        int cx = (i0 >> 3) ^ (col & 7);
        const ushort* zp = (const ushort*)&Zs[(col * 24 + cx) * 8 + (i0 & 7)];
        ushort o[4];
        #pragma unroll
        for (int r = 0; r < 4; ++r)
            o[r] = f2bf(acc[j][r] + Dd * bf2f(zp[r]));
        *(uint2*)&yT[((size_t)d * BATCH + bb) * SEQ + ch * 64 + i0] = *(uint2*)o;
    }
}

// ---------------- k_gemm_ln v17: dbuf Bs, one barrier per K-step (round-27 best) ----------------
__global__ __launch_bounds__(512) void k_gemm_ln(
    const __hip_bfloat16* __restrict__ yT, const __hip_bfloat16* __restrict__ Wbf,
    const float* __restrict__ x, const float* __restrict__ bout,
    const float* __restrict__ gamma, const float* __restrict__ beta,
    float* __restrict__ out)
{
    __shared__ short Af[32][520];
    __shared__ short Bs[2][512][32];
    __shared__ float red[8][32][2];
    __shared__ float stats[32][2];

    const int tid  = threadIdx.x;
    const int w    = tid >> 6;
    const int lane = tid & 63;
    const int q    = lane >> 4;
    const int m    = lane & 15;
    const int r0   = blockIdx.x * 32;
    const int bq   = r0 >> 11;
    const int l0   = r0 & 2047;

    {
        const int kdb = tid >> 3, lg = (tid & 7) * 4;
        uint2 u[8];
        #pragma unroll
        for (int j = 0; j < 8; ++j)
            u[j] = *(const uint2*)&yT[((size_t)(j * 64 + kdb) * BATCH + bq) * SEQ + l0 + lg];
        #pragma unroll
        for (int j = 0; j < 8; ++j) {
            int kd = j * 64 + kdb;
            Af[lg + 0][kd] = (short)(u[j].x & 0xffff);
            Af[lg + 1][kd] = (short)(u[j].x >> 16);
            Af[lg + 2][kd] = (short)(u[j].y & 0xffff);
            Af[lg + 3][kd] = (short)(u[j].y >> 16);
        }
    }

    short8 nb0, nb1, nb2, nb3;
    const int ob = tid >> 2, jb = tid & 3;
    const int js = (jb ^ (ob & 3)) * 8;
    #define LOADB(k0) { \
        nb0 = *(const short8*)(Wbf + (size_t)(ob      ) * DM + (k0) + jb * 8); \
        nb1 = *(const short8*)(Wbf + (size_t)(ob + 128) * DM + (k0) + jb * 8); \
        nb2 = *(const short8*)(Wbf + (size_t)(ob + 256) * DM + (k0) + jb * 8); \
        nb3 = *(const short8*)(Wbf + (size_t)(ob + 384) * DM + (k0) + jb * 8); }
    #define WRITEB(p) { \
        *(short8*)&Bs[p][ob      ][js] = nb0; \
        *(short8*)&Bs[p][ob + 128][js] = nb1; \
        *(short8*)&Bs[p][ob + 256][js] = nb2; \
        *(short8*)&Bs[p][ob + 384][js] = nb3; }

    LOADB(0);
    WRITEB(0);
    LOADB(32);
    __syncthreads();

    f32x4 acc[2][4];
    #pragma unroll
    for (int a = 0; a < 2; ++a)
        #pragma unroll
        for (int nn = 0; nn < 4; ++nn)
            #pragma unroll
            for (int k = 0; k < 4; ++k) acc[a][nn][k] = 0.f;

    int p = 0;
    for (int k = 0; k < 16; ++k) {
        if (k < 15) WRITEB(p ^ 1);
        if (k < 14) LOADB((k + 2) * 32);
        const int k0 = k * 32;
        short8 a0 = *(const short8*)&Af[m][k0 + q * 8];
        short8 a1 = *(const short8*)&Af[16 + m][k0 + q * 8];
        #pragma unroll
        for (int nf = 0; nf < 4; ++nf) {
            int o = w * 64 + nf * 16 + m;
            short8 bb = *(const short8*)&Bs[p][o][(q ^ (m & 3)) * 8];
            acc[0][nf] = __builtin_amdgcn_mfma_f32_16x16x32_bf16(a0, bb, acc[0][nf], 0, 0, 0);
            acc[1][nf] = __builtin_amdgcn_mfma_f32_16x16x32_bf16(a1, bb, acc[1][nf], 0, 0, 0);
        }
        __syncthreads();
        p ^= 1;
    }
    #undef LOADB
    #undef WRITEB

    float bo[4], ga[4], be[4];
    #pragma unroll
    for (int nf = 0; nf < 4; ++nf) {
        int o = w * 64 + nf * 16 + m;
        bo[nf] = bout[o]; ga[nf] = gamma[o]; be[nf] = beta[o];
    }

    float rs[2][4], rq[2][4];
    #pragma unroll
    for (int mf = 0; mf < 2; ++mf)
        #pragma unroll
        for (int i = 0; i < 4; ++i) { rs[mf][i] = 0.f; rq[mf][i] = 0.f; }

    #pragma unroll
    for (int mf = 0; mf < 2; ++mf)
        #pragma unroll
        for (int nf = 0; nf < 4; ++nf) {
            int o = w * 64 + nf * 16 + m;
            #pragma unroll
            for (int i = 0; i < 4; ++i) {
                int row = mf * 16 + q * 4 + i;
                float zv = acc[mf][nf][i] + bo[nf] + x[(size_t)(r0 + row) * DM + o];
                acc[mf][nf][i] = zv;
                rs[mf][i] += zv;
                rq[mf][i] += zv * zv;
            }
        }

    #pragma unroll
    for (int mask = 1; mask < 16; mask <<= 1) {
        #pragma unroll
        for (int mf = 0; mf < 2; ++mf)
            #pragma unroll
            for (int i = 0; i < 4; ++i) {
                rs[mf][i] += __shfl_xor(rs[mf][i], mask);
                rq[mf][i] += __shfl_xor(rq[mf][i], mask);
            }
    }
    if (m == 0) {
        #pragma unroll
        for (int mf = 0; mf < 2; ++mf)
            #pragma unroll
            for (int i = 0; i < 4; ++i) {
                int row = mf * 16 + q * 4 + i;
                red[w][row][0] = rs[mf][i];
                red[w][row][1] = rq[mf][i];
            }
    }
    __syncthreads();
    if (tid < 32) {
        float s = 0.f, sq = 0.f;
        #pragma unroll
        for (int ww = 0; ww < 8; ++ww) { s += red[ww][tid][0]; sq += red[ww][tid][1]; }
        float mu  = s * (1.f / DM);
        float var = sq * (1.f / DM) - mu * mu;
        stats[tid][0] = mu;
        stats[tid][1] = 1.f / sqrtf(var + LN_EPS);
    }
    __syncthreads();

    #pragma unroll
    for (int mf = 0; mf < 2; ++mf)
        #pragma unroll
        for (int i = 0; i < 4; ++i) {
            int row = mf * 16 + q * 4 + i;
            float mu = stats[row][0], rstd = stats[row][1];
            #pragma unroll
            for (int nf = 0; nf < 4; ++nf) {
                int o = w * 64 + nf * 16 + m;
                out[(size_t)(r0 + row) * DM + o] =
                    ga[nf] * (acc[mf][nf][i] - mu) * rstd + be[nf];
            }
        }
}

// ---------------- launcher ----------------
extern "C" void kernel_launch(void* const* d_in, const int* in_sizes, int n_in,
                              void* d_out, int out_size, void* d_ws, size_t ws_size,
                              hipStream_t stream)
{
    const float* x    = (const float*)d_in[0];
    const float* logA = (const float*)d_in[1];
    const float* Aim  = (const float*)d_in[2];
    const float* Bp   = (const float*)d_in[3];
    const float* Cp   = (const float*)d_in[4];
    const float* Dp   = (const float*)d_in[5];
    const float* W    = (const float*)d_in[6];
    const float* bo   = (const float*)d_in[7];
    const float* ga   = (const float*)d_in[8];
    const float* be   = (const float*)d_in[9];

    char* ws = (char*)d_ws;
    __hip_bfloat16* Wbf = (__hip_bfloat16*)ws;                   // 512 KiB @ 0
    __hip_bfloat16* xT  = (__hip_bfloat16*)(ws + (3u << 20));    // 8 MiB    @ 3M
    __hip_bfloat16* yT  = (__hip_bfloat16*)(ws + (41u << 20));   // 8 MiB    @ 41M

    k_prep   <<<3072, 256, 0, stream>>>(x, W, xT, Wbf);
    k_ssm    <<<DM, 512, 0, stream>>>(logA, Aim, Bp, Cp, xT, Dp, yT);
    k_gemm_ln<<<(BATCH * SEQ) / 32, 512, 0, stream>>>(yT, Wbf, x, bo, ga, be, (float*)d_out);
}